// Round 14
// baseline (1540.609 us; speedup 1.0000x reference)
//
#include <hip/hip_runtime.h>

#define S_   1024
#define ND   30
#define EPS_ 1e-6f

typedef __attribute__((ext_vector_type(8))) short bf16x8;
typedef __attribute__((ext_vector_type(4))) float f32x4;

// sign of e_a * e_b in Cl(4,1): returns 1 if negative, 0 if positive.
__device__ __forceinline__ int cayley_neg(int a, int b) {
    int par = 0;
    for (int t = a >> 1; t; t >>= 1) par ^= __popc(t & b) & 1;
    par ^= ((a & b) >> 4) & 1;   // metric: generator 4 has e4*e4 = -1
    return par & 1;
}

__device__ __forceinline__ float sflip(float v, unsigned bit) {
    return __uint_as_float(__float_as_uint(v) ^ (bit << 31));
}

// exact fp32 -> bf16_hi + bf16_lo split (truncation; v - hi is exact)
__device__ __forceinline__ void split2(float v, ushort& hi, ushort& lo) {
    unsigned bv = __float_as_uint(v);
    hi = (ushort)(bv >> 16);
    float hv = __uint_as_float(bv & 0xffff0000u);
    lo = (ushort)(__float_as_uint(v - hv) >> 16);
}

// cross-lane xor-1 / xor-2 on the VALU (DPP quad_perm) instead of the DS pipe
// (R11-verified). xor4/8/16 stay on __shfl_xor: the R12/R13 DPP/permlane tail
// is the prime suspect for the 0.13 failure (permlane16_swap inline asm with
// two "+v" operands from the same value can be register-coalesced -> self-swap
// corrupts ss -> O(1) mis-normalization).
__device__ __forceinline__ float dpp_xor1(float v) {
    return __int_as_float(__builtin_amdgcn_update_dpp(
        0, __float_as_int(v), 0xB1 /*quad_perm 1,0,3,2*/, 0xF, 0xF, true));
}
__device__ __forceinline__ float dpp_xor2(float v) {
    return __int_as_float(__builtin_amdgcn_update_dpp(
        0, __float_as_int(v), 0x4E /*quad_perm 2,3,0,1*/, 0xF, 0xF, true));
}

// lgkmcnt-only barrier (never drains vmcnt -> global stores/loads float freely)
#define BAR() asm volatile("s_waitcnt lgkmcnt(0)\n\ts_barrier" ::: "memory")

__launch_bounds__(512, 2)
__global__ void versor_kernel(const float* __restrict__ x,
                              const float* __restrict__ W_in,
                              const float* __restrict__ b_in,
                              const float* __restrict__ w_h,
                              const float* __restrict__ w_x,
                              const float* __restrict__ W_out,
                              const float* __restrict__ b_out,
                              float* __restrict__ out) {
    const int b   = blockIdx.x;
    const int tid = threadIdx.x;
    const int w   = tid >> 6;        // wave 0..7 -> output channels {2w, 2w+1}
    const int ln  = tid & 63;        // lane in wave
    const int g   = ln >> 4;         // k-chunk (A/B frag) / m_mid (C frag) / sel
    const int cl  = ln & 15;         // A row-in-tile, B/C col-in-tile
    const int op  = ln >> 5;         // o' in {0,1}
    const int oo  = 2 * w + op;      // this thread's h channel
    const int kk  = ln & 31;         // this thread's h component
    const int oc  = tid >> 5;        // out-phase channel group (== oo)
    const int lc  = tid & 31;        // out-phase column lane   (== kk)

    // G (=[h | xe]) in MFMA A-fragment layout, bf16 hi/lo, double-buffered:
    // elem = mt*512 + (ich>>3)*128 + (m&15)*8 + (ich&7)
    __shared__ ushort ghi[2][1024];
    __shared__ ushort glo[2][1024];
    __shared__ __align__(16) float hlds[2][512];   // h_{s+1} at parity (s+1)&1
    __shared__ float red[2][512];

    // ---- B fragments (W, step-constant): lane holds B[k=8g+j][nt*16+cl] ----
    bf16x8 bh[2][2], bl[2][2];       // [o'][nt]
    #pragma unroll
    for (int opi = 0; opi < 2; ++opi) {
        #pragma unroll
        for (int nt = 0; nt < 2; ++nt) {
            const int o = 2 * w + opi;
            const int n = nt * 16 + cl;
            #pragma unroll
            for (int j = 0; j < 8; ++j) {
                const int k = g * 8 + j;
                float wv = (k < 16) ? w_h[(o * 16 + k) * 32 + n]
                                    : w_x[(o * 16 + (k - 16)) * 32 + n];
                ushort h_, l_; split2(wv, h_, l_);
                bh[opi][nt][j] = (short)h_;
                bl[opi][nt][j] = (short)l_;
            }
        }
    }

    float win_reg[ND];               // column tid of W_in
    #pragma unroll
    for (int p = 0; p < ND; ++p) win_reg[p] = W_in[p * 512 + tid];
    const float bin_reg = b_in[tid];

    const int pc = (lc < ND) ? lc : 0;
    float wout[32];                  // W_out[(oc*32+jj)][pc]
    #pragma unroll
    for (int jj = 0; jj < 32; ++jj) wout[jj] = W_out[(oc * 32 + jj) * ND + pc];
    const float bout_reg = (tid < ND) ? b_out[tid] : 0.0f;

    // sign mask: bit (mt*8 + nt*4 + r) = s(m,n) for m=mt*16+g*4+r, n=nt*16+cl
    unsigned smask = 0;
    for (int mt = 0; mt < 2; ++mt)
        for (int nt = 0; nt < 2; ++nt)
            for (int r = 0; r < 4; ++r) {
                int m = mt * 16 + g * 4 + r;
                int n = nt * 16 + cl;
                smask |= (unsigned)cayley_neg(m, n) << (mt * 8 + nt * 4 + r);
            }

    // fixed LDS element offsets
    const int eh = (kk >> 4) * 512 + (oo >> 3) * 128 + (kk & 15) * 8 + (oo & 7);
    const int ex = (lc >> 4) * 512 + (2 + (oc >> 3)) * 128 + (lc & 15) * 8 + (oc & 7);
    const int ea = g * 128 + cl * 8;     // A-frag read base (+512 for mt=1)

    ghi[0][eh] = 0; glo[0][eh] = 0;      // h_0 = 0 (parity-0 h slots)

    float h_reg = 0.0f, xv_prev = 0.0f;
    const float* xrow = x   + (size_t)b * S_ * ND;
    float*       orow = out + (size_t)b * S_ * ND;
    const f32x4 z4 = {0.f, 0.f, 0.f, 0.f};

    // iter s computes h_{s+1} and finishes out[s-1]; iter S_ finishes out[S_-1]
    for (int s = 0; s <= S_; ++s) {
        const int p = s & 1;

        // ---- stage 1: xe (uniform x loads), 4-way ILP, -> G[p] ----
        float xv_cur = 0.0f;
        if (s < S_) {
            const float* xp = xrow + s * ND;
            xv_cur = (tid < ND) ? xp[tid] : 0.0f;
            float xe0 = bin_reg, xe1 = 0.f, xe2 = 0.f, xe3 = 0.f;
            #pragma unroll
            for (int q = 0; q < 28; q += 4) {
                xe0 = fmaf(xp[q + 0], win_reg[q + 0], xe0);
                xe1 = fmaf(xp[q + 1], win_reg[q + 1], xe1);
                xe2 = fmaf(xp[q + 2], win_reg[q + 2], xe2);
                xe3 = fmaf(xp[q + 3], win_reg[q + 3], xe3);
            }
            xe0 = fmaf(xp[28], win_reg[28], xe0);
            xe1 = fmaf(xp[29], win_reg[29], xe1);
            float xe = (xe0 + xe1) + (xe2 + xe3);
            ushort xh, xl; split2(xe, xh, xl);
            ghi[p][ex] = xh; glo[p][ex] = xl;
        }

        // ---- stage 2: out[s-1] partials from h_s via uniform b128 broadcast ----
        if (s > 0) {
            const float* hp = &hlds[p][oc * 32];
            float oacc = 0.0f;
            #pragma unroll
            for (int qq = 0; qq < 8; ++qq) {
                float4 hv = *(const float4*)(hp + qq * 4);
                oacc = fmaf(hv.x, wout[qq * 4 + 0], oacc);
                oacc = fmaf(hv.y, wout[qq * 4 + 1], oacc);
                oacc = fmaf(hv.z, wout[qq * 4 + 2], oacc);
                oacc = fmaf(hv.w, wout[qq * 4 + 3], oacc);
            }
            red[p][oc * 32 + lc] = oacc;
        }

        BAR();   // the ONE barrier: G[p] (h from s-1 tail, xe), red[p] visible

        // ---- stage 3: finish out[s-1] (global store, never drained) ----
        if (s > 0 && tid < ND) {
            float s0 = 0.f, s1 = 0.f, s2 = 0.f, s3 = 0.f;
            #pragma unroll
            for (int jg = 0; jg < 16; jg += 4) {
                s0 += red[p][(jg + 0) * 32 + tid];
                s1 += red[p][(jg + 1) * 32 + tid];
                s2 += red[p][(jg + 2) * 32 + tid];
                s3 += red[p][(jg + 3) * 32 + tid];
            }
            float ov = xv_prev + bout_reg + ((s0 + s1) + (s2 + s3));
            orow[(size_t)(s - 1) * ND + tid] = ov;
        }

        if (s < S_) {
            // ---- stage 4: A-fragments + 32 MFMA (FULL 4-term split, R11-exact) ----
            bf16x8 ah0 = *(const bf16x8*)&ghi[p][ea];
            bf16x8 ah1 = *(const bf16x8*)&ghi[p][ea + 512];
            bf16x8 al0 = *(const bf16x8*)&glo[p][ea];
            bf16x8 al1 = *(const bf16x8*)&glo[p][ea + 512];

            f32x4 acc[2][2][2];      // [o'][mt][nt]
            #pragma unroll
            for (int opi = 0; opi < 2; ++opi) {
                #pragma unroll
                for (int nt = 0; nt < 2; ++nt) {
                    f32x4 t = __builtin_amdgcn_mfma_f32_16x16x32_bf16(al0, bl[opi][nt], z4, 0, 0, 0);
                    t = __builtin_amdgcn_mfma_f32_16x16x32_bf16(ah0, bl[opi][nt], t, 0, 0, 0);
                    t = __builtin_amdgcn_mfma_f32_16x16x32_bf16(al0, bh[opi][nt], t, 0, 0, 0);
                    acc[opi][0][nt] = __builtin_amdgcn_mfma_f32_16x16x32_bf16(ah0, bh[opi][nt], t, 0, 0, 0);
                    f32x4 u = __builtin_amdgcn_mfma_f32_16x16x32_bf16(al1, bl[opi][nt], z4, 0, 0, 0);
                    u = __builtin_amdgcn_mfma_f32_16x16x32_bf16(ah1, bl[opi][nt], u, 0, 0, 0);
                    u = __builtin_amdgcn_mfma_f32_16x16x32_bf16(al1, bh[opi][nt], u, 0, 0, 0);
                    acc[opi][1][nt] = __builtin_amdgcn_mfma_f32_16x16x32_bf16(ah1, bh[opi][nt], u, 0, 0, 0);
                }
            }

            // ---- stage 5: sign + XOR-fold (R11-exact) ----
            float Y[2][2][4];
            #pragma unroll
            for (int opi = 0; opi < 2; ++opi)
                #pragma unroll
                for (int nt = 0; nt < 2; ++nt)
                    #pragma unroll
                    for (int r = 0; r < 4; ++r) {
                        float v0 = sflip(acc[opi][0][nt][r],     (smask >> (nt * 4 + r)) & 1u);
                        float v1 = sflip(acc[opi][1][nt ^ 1][r], (smask >> (8 + (nt ^ 1) * 4 + r)) & 1u);
                        Y[opi][nt][r] = v0 + v1;
                    }
            float Z[2][2];
            #pragma unroll
            for (int opi = 0; opi < 2; ++opi) {
                #pragma unroll
                for (int kt = 0; kt < 2; ++kt) {
                    float ya0 = Y[opi][kt][0] + dpp_xor1(Y[opi][kt][1]);
                    float ya2 = Y[opi][kt][2] + dpp_xor1(Y[opi][kt][3]);
                    float z = ya0 + dpp_xor2(ya2);
                    z += __shfl_xor(z, 20, 64);
                    z += __shfl_xor(z, 40, 64);
                    Z[opi][kt] = z;
                }
            }
            float d0 = __shfl(Z[0][0], cl, 64);
            float d1 = __shfl(Z[0][1], cl, 64);
            float d2 = __shfl(Z[1][0], cl, 64);
            float d3 = __shfl(Z[1][1], cl, 64);
            const float delta = (g == 0) ? d0 : (g == 1) ? d1 : (g == 2) ? d2 : d3;

            // ---- stage 6: residual + L2 norm (R11-exact reduction tail) ----
            float hc = h_reg + delta;
            float ss = hc * hc;
            ss += dpp_xor1(ss);          // xor1 (quad_perm, R11-verified)
            ss += dpp_xor2(ss);          // xor2 (quad_perm, R11-verified)
            ss += __shfl_xor(ss, 4, 32);
            ss += __shfl_xor(ss, 8, 32);
            ss += __shfl_xor(ss, 16, 32);
            h_reg = hc / (sqrtf(ss) + EPS_);

            // ---- stage 7: h_{s+1} -> parity p^1 ----
            ushort hh, hl; split2(h_reg, hh, hl);
            ghi[p ^ 1][eh] = hh; glo[p ^ 1][eh] = hl;
            hlds[p ^ 1][oo * 32 + kk] = h_reg;       // slot == tid
        }

        xv_prev = xv_cur;
    }
}

extern "C" void kernel_launch(void* const* d_in, const int* in_sizes, int n_in,
                              void* d_out, int out_size, void* d_ws, size_t ws_size,
                              hipStream_t stream) {
    const float* x     = (const float*)d_in[0];
    const float* W_in  = (const float*)d_in[1];
    const float* b_in  = (const float*)d_in[2];
    const float* w_h   = (const float*)d_in[3];
    const float* w_x   = (const float*)d_in[4];
    const float* W_out = (const float*)d_in[5];
    const float* b_out = (const float*)d_in[6];
    float* outp = (float*)d_out;

    versor_kernel<<<256, 512, 0, stream>>>(x, W_in, b_in, w_h, w_x, W_out, b_out, outp);
}

// Round 15
// 1419.939 us; speedup vs baseline: 1.0850x; 1.0850x over previous
//
#include <hip/hip_runtime.h>

#define S_   1024
#define ND   30
#define EPS_ 1e-6f

typedef __attribute__((ext_vector_type(8))) short bf16x8;
typedef __attribute__((ext_vector_type(4))) float f32x4;
typedef __attribute__((ext_vector_type(2))) _Float16 h2;
typedef __attribute__((ext_vector_type(8))) _Float16 h8;

// sign of e_a * e_b in Cl(4,1): returns 1 if negative, 0 if positive.
__device__ __forceinline__ int cayley_neg(int a, int b) {
    int par = 0;
    for (int t = a >> 1; t; t >>= 1) par ^= __popc(t & b) & 1;
    par ^= ((a & b) >> 4) & 1;   // metric: generator 4 has e4*e4 = -1
    return par & 1;
}

__device__ __forceinline__ float sflip(float v, unsigned bit) {
    return __uint_as_float(__float_as_uint(v) ^ (bit << 31));
}

// exact fp32 -> bf16_hi + bf16_lo split (truncation; v - hi is exact)
__device__ __forceinline__ void split2(float v, ushort& hi, ushort& lo) {
    unsigned bv = __float_as_uint(v);
    hi = (ushort)(bv >> 16);
    float hv = __uint_as_float(bv & 0xffff0000u);
    lo = (ushort)(__float_as_uint(v - hv) >> 16);
}

__device__ __forceinline__ ushort f2h(float v) {
    _Float16 h = (_Float16)v;
    ushort u;
    __builtin_memcpy(&u, &h, 2);
    return u;
}

// cross-lane xor-1 / xor-2 on the VALU (DPP quad_perm) — R11/R14-verified.
__device__ __forceinline__ float dpp_xor1(float v) {
    return __int_as_float(__builtin_amdgcn_update_dpp(
        0, __float_as_int(v), 0xB1 /*quad_perm 1,0,3,2*/, 0xF, 0xF, true));
}
__device__ __forceinline__ float dpp_xor2(float v) {
    return __int_as_float(__builtin_amdgcn_update_dpp(
        0, __float_as_int(v), 0x4E /*quad_perm 2,3,0,1*/, 0xF, 0xF, true));
}

// lgkmcnt-only barrier (never drains vmcnt -> global stores/loads float freely)
#define BAR() asm volatile("s_waitcnt lgkmcnt(0)\n\ts_barrier" ::: "memory")

__launch_bounds__(512, 2)
__global__ void versor_kernel(const float* __restrict__ x,
                              const float* __restrict__ W_in,
                              const float* __restrict__ b_in,
                              const float* __restrict__ w_h,
                              const float* __restrict__ w_x,
                              const float* __restrict__ W_out,
                              const float* __restrict__ b_out,
                              float* __restrict__ out) {
    const int b   = blockIdx.x;
    const int tid = threadIdx.x;
    const int w   = tid >> 6;        // wave 0..7 -> output channels {2w, 2w+1}
    const int ln  = tid & 63;        // lane in wave
    const int g   = ln >> 4;         // k-chunk (A/B frag) / m_mid (C frag) / sel
    const int cl  = ln & 15;         // A row-in-tile, B/C col-in-tile
    const int op  = ln >> 5;         // o' in {0,1}
    const int oo  = 2 * w + op;      // this thread's h channel
    const int kk  = ln & 31;         // this thread's h component
    const int oc  = tid >> 5;        // out-phase channel group (== oo)
    const int lc  = tid & 31;        // out-phase column lane   (== kk)

    // G (=[h | xe]) in MFMA A-fragment layout, bf16 hi/lo, double-buffered:
    // elem = mt*512 + (ich>>3)*128 + (m&15)*8 + (ich&7)
    __shared__ ushort ghi[2][1024];
    __shared__ ushort glo[2][1024];
    __shared__ __align__(16) ushort hf[2][512];    // h in f16, out-phase layout
    __shared__ float red[2][512];

    // ---- B fragments (W, step-constant): lane holds B[k=8g+j][nt*16+cl] ----
    bf16x8 bh[2][2], bl[2][2];       // [o'][nt]
    #pragma unroll
    for (int opi = 0; opi < 2; ++opi) {
        #pragma unroll
        for (int nt = 0; nt < 2; ++nt) {
            const int o = 2 * w + opi;
            const int n = nt * 16 + cl;
            #pragma unroll
            for (int j = 0; j < 8; ++j) {
                const int k = g * 8 + j;
                float wv = (k < 16) ? w_h[(o * 16 + k) * 32 + n]
                                    : w_x[(o * 16 + (k - 16)) * 32 + n];
                ushort h_, l_; split2(wv, h_, l_);
                bh[opi][nt][j] = (short)h_;
                bl[opi][nt][j] = (short)l_;
            }
        }
    }

    float win_reg[ND];               // column tid of W_in
    #pragma unroll
    for (int p = 0; p < ND; ++p) win_reg[p] = W_in[p * 512 + tid];
    const float bin_reg = b_in[tid];

    const int pc = (lc < ND) ? lc : 0;
    h2 wout_h2[16];                  // W_out[(oc*32+2j, +2j+1)][pc] as f16 pairs
    #pragma unroll
    for (int j = 0; j < 16; ++j) {
        wout_h2[j][0] = (_Float16)W_out[(oc * 32 + 2 * j) * ND + pc];
        wout_h2[j][1] = (_Float16)W_out[(oc * 32 + 2 * j + 1) * ND + pc];
    }
    const float bout_reg = (tid < ND) ? b_out[tid] : 0.0f;

    // sign mask: bit (mt*8 + nt*4 + r) = s(m,n) for m=mt*16+g*4+r, n=nt*16+cl
    unsigned smask = 0;
    for (int mt = 0; mt < 2; ++mt)
        for (int nt = 0; nt < 2; ++nt)
            for (int r = 0; r < 4; ++r) {
                int m = mt * 16 + g * 4 + r;
                int n = nt * 16 + cl;
                smask |= (unsigned)cayley_neg(m, n) << (mt * 8 + nt * 4 + r);
            }

    // fixed LDS element offsets
    const int eh = (kk >> 4) * 512 + (oo >> 3) * 128 + (kk & 15) * 8 + (oo & 7);
    const int ex = (lc >> 4) * 512 + (2 + (oc >> 3)) * 128 + (lc & 15) * 8 + (oc & 7);
    const int ea = g * 128 + cl * 8;     // A-frag read base (+512 for mt=1)

    // redistribute source lane: Z[opi][kt] at lane l holds delta[opi][kt*16+f(l)],
    // f(l) = (l&15) ^ ((g&1)<<2) ^ ((g>>1)<<3); need f(l_src)=cl with g(l_src)=g.
    const int l_src = (g << 4) | (cl ^ ((g & 1) << 2) ^ ((g >> 1) << 3));

    ghi[0][eh] = 0; glo[0][eh] = 0;      // h_0 = 0 (parity-0 h slots)

    float h_reg = 0.0f, xv_prev = 0.0f;
    const float* xrow = x   + (size_t)b * S_ * ND;
    float*       orow = out + (size_t)b * S_ * ND;
    const f32x4 z4 = {0.f, 0.f, 0.f, 0.f};

    // iter s computes h_{s+1} and finishes out[s-1]; iter S_ finishes out[S_-1]
    for (int s = 0; s <= S_; ++s) {
        const int p = s & 1;

        // ---- stage 1: xe (uniform x loads), 4-way ILP, -> G[p] ----
        float xv_cur = 0.0f;
        if (s < S_) {
            const float* xp = xrow + s * ND;
            xv_cur = (tid < ND) ? xp[tid] : 0.0f;
            float xe0 = bin_reg, xe1 = 0.f, xe2 = 0.f, xe3 = 0.f;
            #pragma unroll
            for (int q = 0; q < 28; q += 4) {
                xe0 = fmaf(xp[q + 0], win_reg[q + 0], xe0);
                xe1 = fmaf(xp[q + 1], win_reg[q + 1], xe1);
                xe2 = fmaf(xp[q + 2], win_reg[q + 2], xe2);
                xe3 = fmaf(xp[q + 3], win_reg[q + 3], xe3);
            }
            xe0 = fmaf(xp[28], win_reg[28], xe0);
            xe1 = fmaf(xp[29], win_reg[29], xe1);
            float xe = (xe0 + xe1) + (xe2 + xe3);
            ushort xh, xl; split2(xe, xh, xl);
            ghi[p][ex] = xh; glo[p][ex] = xl;
        }

        // ---- stage 2: out[s-1] partials from h_s (f16 dot2, 4x b128 reads;
        // hf[p] written by THIS half-wave last iter -> same-wave ordering) ----
        if (s > 0) {
            const ushort* hp = &hf[p][oc * 32];
            float oacc = 0.0f;
            #pragma unroll
            for (int qq = 0; qq < 4; ++qq) {
                h8 hv = *(const h8*)(hp + qq * 8);
                h2 a0 = {hv[0], hv[1]}, a1 = {hv[2], hv[3]};
                h2 a2 = {hv[4], hv[5]}, a3 = {hv[6], hv[7]};
                oacc = __builtin_amdgcn_fdot2(a0, wout_h2[qq * 4 + 0], oacc, false);
                oacc = __builtin_amdgcn_fdot2(a1, wout_h2[qq * 4 + 1], oacc, false);
                oacc = __builtin_amdgcn_fdot2(a2, wout_h2[qq * 4 + 2], oacc, false);
                oacc = __builtin_amdgcn_fdot2(a3, wout_h2[qq * 4 + 3], oacc, false);
            }
            red[p][oc * 32 + lc] = oacc;
        }

        BAR();   // the ONE barrier: G[p] (h from s-1 tail, xe), red[p] visible

        // ---- stage 3: finish out[s-1] (global store, never drained) ----
        if (s > 0 && tid < ND) {
            float s0 = 0.f, s1 = 0.f, s2 = 0.f, s3 = 0.f;
            #pragma unroll
            for (int jg = 0; jg < 16; jg += 4) {
                s0 += red[p][(jg + 0) * 32 + tid];
                s1 += red[p][(jg + 1) * 32 + tid];
                s2 += red[p][(jg + 2) * 32 + tid];
                s3 += red[p][(jg + 3) * 32 + tid];
            }
            float ov = xv_prev + bout_reg + ((s0 + s1) + (s2 + s3));
            orow[(size_t)(s - 1) * ND + tid] = ov;
        }

        if (s < S_) {
            // ---- stage 4: A-fragments + 32 MFMA (FULL 4-term split, R11-exact) ----
            bf16x8 ah0 = *(const bf16x8*)&ghi[p][ea];
            bf16x8 ah1 = *(const bf16x8*)&ghi[p][ea + 512];
            bf16x8 al0 = *(const bf16x8*)&glo[p][ea];
            bf16x8 al1 = *(const bf16x8*)&glo[p][ea + 512];

            f32x4 acc[2][2][2];      // [o'][mt][nt]
            #pragma unroll
            for (int opi = 0; opi < 2; ++opi) {
                #pragma unroll
                for (int nt = 0; nt < 2; ++nt) {
                    f32x4 t = __builtin_amdgcn_mfma_f32_16x16x32_bf16(al0, bl[opi][nt], z4, 0, 0, 0);
                    t = __builtin_amdgcn_mfma_f32_16x16x32_bf16(ah0, bl[opi][nt], t, 0, 0, 0);
                    t = __builtin_amdgcn_mfma_f32_16x16x32_bf16(al0, bh[opi][nt], t, 0, 0, 0);
                    acc[opi][0][nt] = __builtin_amdgcn_mfma_f32_16x16x32_bf16(ah0, bh[opi][nt], t, 0, 0, 0);
                    f32x4 u = __builtin_amdgcn_mfma_f32_16x16x32_bf16(al1, bl[opi][nt], z4, 0, 0, 0);
                    u = __builtin_amdgcn_mfma_f32_16x16x32_bf16(ah1, bl[opi][nt], u, 0, 0, 0);
                    u = __builtin_amdgcn_mfma_f32_16x16x32_bf16(al1, bh[opi][nt], u, 0, 0, 0);
                    acc[opi][1][nt] = __builtin_amdgcn_mfma_f32_16x16x32_bf16(ah1, bh[opi][nt], u, 0, 0, 0);
                }
            }

            // ---- stage 5: sign + XOR-fold (R11-exact values) ----
            float Y[2][2][4];
            #pragma unroll
            for (int opi = 0; opi < 2; ++opi)
                #pragma unroll
                for (int nt = 0; nt < 2; ++nt)
                    #pragma unroll
                    for (int r = 0; r < 4; ++r) {
                        float v0 = sflip(acc[opi][0][nt][r],     (smask >> (nt * 4 + r)) & 1u);
                        float v1 = sflip(acc[opi][1][nt ^ 1][r], (smask >> (8 + (nt ^ 1) * 4 + r)) & 1u);
                        Y[opi][nt][r] = v0 + v1;
                    }
            float Z[2][2];
            #pragma unroll
            for (int opi = 0; opi < 2; ++opi) {
                #pragma unroll
                for (int kt = 0; kt < 2; ++kt) {
                    float ya0 = Y[opi][kt][0] + dpp_xor1(Y[opi][kt][1]);
                    float ya2 = Y[opi][kt][2] + dpp_xor1(Y[opi][kt][3]);
                    float z = ya0 + dpp_xor2(ya2);
                    z += __shfl_xor(z, 20, 64);
                    z += __shfl_xor(z, 40, 64);
                    Z[opi][kt] = z;
                }
            }
            // select-by-own-g first (3 cndmask), then ONE bpermute from l_src
            float za  = (g & 2) ? Z[1][0] : Z[0][0];
            float zb  = (g & 2) ? Z[1][1] : Z[0][1];
            float sel = (g & 1) ? zb : za;
            const float delta = __shfl(sel, l_src, 64);

            // ---- stage 6: residual + L2 norm (R14-exact reduction tail) ----
            float hc = h_reg + delta;
            float ss = hc * hc;
            ss += dpp_xor1(ss);
            ss += dpp_xor2(ss);
            ss += __shfl_xor(ss, 4, 32);
            ss += __shfl_xor(ss, 8, 32);
            ss += __shfl_xor(ss, 16, 32);
            h_reg = hc / (sqrtf(ss) + EPS_);

            // ---- stage 7: h_{s+1} -> parity p^1 (bf16 hi/lo for MFMA, f16 for out) ----
            ushort hh, hl; split2(h_reg, hh, hl);
            ghi[p ^ 1][eh] = hh; glo[p ^ 1][eh] = hl;
            hf[p ^ 1][oo * 32 + kk] = f2h(h_reg);    // slot == tid
        }

        xv_prev = xv_cur;
    }
}

extern "C" void kernel_launch(void* const* d_in, const int* in_sizes, int n_in,
                              void* d_out, int out_size, void* d_ws, size_t ws_size,
                              hipStream_t stream) {
    const float* x     = (const float*)d_in[0];
    const float* W_in  = (const float*)d_in[1];
    const float* b_in  = (const float*)d_in[2];
    const float* w_h   = (const float*)d_in[3];
    const float* w_x   = (const float*)d_in[4];
    const float* W_out = (const float*)d_in[5];
    const float* b_out = (const float*)d_in[6];
    float* outp = (float*)d_out;

    versor_kernel<<<256, 512, 0, stream>>>(x, W_in, b_in, w_h, w_x, W_out, b_out, outp);
}

// Round 17
// 1394.487 us; speedup vs baseline: 1.1048x; 1.0183x over previous
//
#include <hip/hip_runtime.h>

#define S_   1024
#define ND   30
#define EPS_ 1e-6f

typedef __attribute__((ext_vector_type(8))) short bf16x8;
typedef __attribute__((ext_vector_type(4))) float f32x4;
typedef __attribute__((ext_vector_type(2))) _Float16 h2;
typedef __attribute__((ext_vector_type(8))) _Float16 h8;

// sign of e_a * e_b in Cl(4,1): returns 1 if negative, 0 if positive.
__device__ __forceinline__ int cayley_neg(int a, int b) {
    int par = 0;
    for (int t = a >> 1; t; t >>= 1) par ^= __popc(t & b) & 1;
    par ^= ((a & b) >> 4) & 1;   // metric: generator 4 has e4*e4 = -1
    return par & 1;
}

// exact fp32 -> bf16_hi + bf16_lo split (truncation; v - hi is exact)
__device__ __forceinline__ void split2(float v, ushort& hi, ushort& lo) {
    unsigned bv = __float_as_uint(v);
    hi = (ushort)(bv >> 16);
    float hv = __uint_as_float(bv & 0xffff0000u);
    lo = (ushort)(__float_as_uint(v - hv) >> 16);
}

__device__ __forceinline__ ushort f2h(float v) {
    _Float16 h = (_Float16)v;
    ushort u;
    __builtin_memcpy(&u, &h, 2);
    return u;
}

// cross-lane xor-1 / xor-2 on the VALU (DPP quad_perm) — verified R11/R14/R15.
// NOTE (R12/R13/R16 post-mortems): the mirror/ror/permlane16-swap DPP family
// consistently produced ~0.13 absmax failures (wrong-partner sums in the norm).
// xor4/8/16 MUST stay on __shfl_xor — do not revisit.
__device__ __forceinline__ float dpp_xor1(float v) {
    return __int_as_float(__builtin_amdgcn_update_dpp(
        0, __float_as_int(v), 0xB1 /*quad_perm 1,0,3,2*/, 0xF, 0xF, true));
}
__device__ __forceinline__ float dpp_xor2(float v) {
    return __int_as_float(__builtin_amdgcn_update_dpp(
        0, __float_as_int(v), 0x4E /*quad_perm 2,3,0,1*/, 0xF, 0xF, true));
}

// lgkmcnt-only barrier (never drains vmcnt -> global stores/loads float freely)
#define BAR() asm volatile("s_waitcnt lgkmcnt(0)\n\ts_barrier" ::: "memory")

__launch_bounds__(512, 2)
__global__ void versor_kernel(const float* __restrict__ x,
                              const float* __restrict__ W_in,
                              const float* __restrict__ b_in,
                              const float* __restrict__ w_h,
                              const float* __restrict__ w_x,
                              const float* __restrict__ W_out,
                              const float* __restrict__ b_out,
                              float* __restrict__ out) {
    const int b   = blockIdx.x;
    const int tid = threadIdx.x;
    const int w   = tid >> 6;        // wave 0..7 -> output channels {2w, 2w+1}
    const int ln  = tid & 63;        // lane in wave
    const int g   = ln >> 4;         // k-chunk (A/B frag) / m_mid (C frag) / sel
    const int cl  = ln & 15;         // A row-in-tile, B/C col-in-tile
    const int op  = ln >> 5;         // o' in {0,1}
    const int oo  = 2 * w + op;      // this thread's h channel
    const int kk  = ln & 31;         // this thread's h component
    const int oc  = tid >> 5;        // out-phase channel group (== oo)
    const int lc  = tid & 31;        // out-phase column lane   (== kk)

    // G (=[h | xe]) in MFMA A-fragment layout, bf16 hi/lo, double-buffered:
    // elem = mt*512 + (ich>>3)*128 + (m&15)*8 + (ich&7)
    __shared__ ushort ghi[2][1024];
    __shared__ ushort glo[2][1024];
    __shared__ __align__(16) ushort hf[2][512];    // h in f16, out-phase layout
    __shared__ float red[2][512];

    // ---- B fragments (W, step-constant): lane holds B[k=8g+j][nt*16+cl] ----
    bf16x8 bh[2][2], bl[2][2];       // [o'][nt]
    #pragma unroll
    for (int opi = 0; opi < 2; ++opi) {
        #pragma unroll
        for (int nt = 0; nt < 2; ++nt) {
            const int o = 2 * w + opi;
            const int n = nt * 16 + cl;
            #pragma unroll
            for (int j = 0; j < 8; ++j) {
                const int k = g * 8 + j;
                float wv = (k < 16) ? w_h[(o * 16 + k) * 32 + n]
                                    : w_x[(o * 16 + (k - 16)) * 32 + n];
                ushort h_, l_; split2(wv, h_, l_);
                bh[opi][nt][j] = (short)h_;
                bl[opi][nt][j] = (short)l_;
            }
        }
    }

    float win_reg[ND];               // column tid of W_in
    #pragma unroll
    for (int p = 0; p < ND; ++p) win_reg[p] = W_in[p * 512 + tid];
    const float bin_reg = b_in[tid];

    const int pc = (lc < ND) ? lc : 0;
    h2 wout_h2[16];                  // W_out[(oc*32+2j, +2j+1)][pc] as f16 pairs
    #pragma unroll
    for (int j = 0; j < 16; ++j) {
        wout_h2[j][0] = (_Float16)W_out[(oc * 32 + 2 * j) * ND + pc];
        wout_h2[j][1] = (_Float16)W_out[(oc * 32 + 2 * j + 1) * ND + pc];
    }
    const float bout_reg = (tid < ND) ? b_out[tid] : 0.0f;

    // signs as +-1.0f: sgn[mt*8+nt*4+r] = s(m,n), m=mt*16+g*4+r, n=nt*16+cl.
    // fma(sgn, a, sgn'*b) is a single rounding of (+-a)+(+-b) -> bit-exact
    // vs the xor/add form, 2 ops instead of 3. (Safe: verified identity.)
    float sgn[16];
    for (int mt = 0; mt < 2; ++mt)
        for (int nt = 0; nt < 2; ++nt)
            for (int r = 0; r < 4; ++r) {
                int m = mt * 16 + g * 4 + r;
                int n = nt * 16 + cl;
                sgn[mt * 8 + nt * 4 + r] = cayley_neg(m, n) ? -1.0f : 1.0f;
            }

    // fixed LDS element offsets
    const int eh = (kk >> 4) * 512 + (oo >> 3) * 128 + (kk & 15) * 8 + (oo & 7);
    const int ex = (lc >> 4) * 512 + (2 + (oc >> 3)) * 128 + (lc & 15) * 8 + (oc & 7);
    const int ea = g * 128 + cl * 8;     // A-frag read base (+512 for mt=1)

    // redistribute source lane: Z[opi][kt] at lane l holds delta[opi][kt*16+f(l)],
    // f(l) = (l&15) ^ ((g&1)<<2) ^ ((g>>1)<<3); need f(l_src)=cl with g(l_src)=g.
    const int l_src = (g << 4) | (cl ^ ((g & 1) << 2) ^ ((g >> 1) << 3));

    ghi[0][eh] = 0; glo[0][eh] = 0;      // h_0 = 0 (parity-0 h slots)

    float h_reg = 0.0f, xv_prev = 0.0f;
    const float* xrow = x   + (size_t)b * S_ * ND;
    float*       orow = out + (size_t)b * S_ * ND;
    const f32x4 z4 = {0.f, 0.f, 0.f, 0.f};

    // iter s computes h_{s+1} and finishes out[s-1]; iter S_ finishes out[S_-1]
    for (int s = 0; s <= S_; ++s) {
        const int p = s & 1;

        // ---- stage 1: xe (uniform x loads), 4-way ILP, -> G[p] ----
        float xv_cur = 0.0f;
        if (s < S_) {
            const float* xp = xrow + s * ND;
            xv_cur = (tid < ND) ? xp[tid] : 0.0f;
            float xe0 = bin_reg, xe1 = 0.f, xe2 = 0.f, xe3 = 0.f;
            #pragma unroll
            for (int q = 0; q < 28; q += 4) {
                xe0 = fmaf(xp[q + 0], win_reg[q + 0], xe0);
                xe1 = fmaf(xp[q + 1], win_reg[q + 1], xe1);
                xe2 = fmaf(xp[q + 2], win_reg[q + 2], xe2);
                xe3 = fmaf(xp[q + 3], win_reg[q + 3], xe3);
            }
            xe0 = fmaf(xp[28], win_reg[28], xe0);
            xe1 = fmaf(xp[29], win_reg[29], xe1);
            float xe = (xe0 + xe1) + (xe2 + xe3);
            ushort xh, xl; split2(xe, xh, xl);
            ghi[p][ex] = xh; glo[p][ex] = xl;
        }

        // ---- stage 2: out[s-1] partials from h_s (f16 dot2, 2 ILP chains;
        // out-path only -> reassociation cannot touch the recurrence) ----
        if (s > 0) {
            const ushort* hp = &hf[p][oc * 32];
            float oa0 = 0.0f, oa1 = 0.0f;
            #pragma unroll
            for (int qq = 0; qq < 2; ++qq) {
                h8 hv0 = *(const h8*)(hp + qq * 8);
                h8 hv1 = *(const h8*)(hp + 16 + qq * 8);
                #pragma unroll
                for (int jj = 0; jj < 4; ++jj) {
                    h2 a0 = {hv0[2 * jj], hv0[2 * jj + 1]};
                    h2 a1 = {hv1[2 * jj], hv1[2 * jj + 1]};
                    oa0 = __builtin_amdgcn_fdot2(a0, wout_h2[qq * 4 + jj], oa0, false);
                    oa1 = __builtin_amdgcn_fdot2(a1, wout_h2[8 + qq * 4 + jj], oa1, false);
                }
            }
            red[p][oc * 32 + lc] = oa0 + oa1;
        }

        BAR();   // the ONE barrier: G[p] (h from s-1 tail, xe), red[p] visible

        // ---- stage 3: finish out[s-1] (global store, never drained) ----
        if (s > 0 && tid < ND) {
            float s0 = 0.f, s1 = 0.f, s2 = 0.f, s3 = 0.f;
            #pragma unroll
            for (int jg = 0; jg < 16; jg += 4) {
                s0 += red[p][(jg + 0) * 32 + tid];
                s1 += red[p][(jg + 1) * 32 + tid];
                s2 += red[p][(jg + 2) * 32 + tid];
                s3 += red[p][(jg + 3) * 32 + tid];
            }
            float ov = xv_prev + bout_reg + ((s0 + s1) + (s2 + s3));
            orow[(size_t)(s - 1) * ND + tid] = ov;
        }

        if (s < S_) {
            // ---- stage 4: A-fragments + 32 MFMA (FULL 4-term split, R11-exact) ----
            bf16x8 ah0 = *(const bf16x8*)&ghi[p][ea];
            bf16x8 ah1 = *(const bf16x8*)&ghi[p][ea + 512];
            bf16x8 al0 = *(const bf16x8*)&glo[p][ea];
            bf16x8 al1 = *(const bf16x8*)&glo[p][ea + 512];

            f32x4 acc[2][2][2];      // [o'][mt][nt]
            #pragma unroll
            for (int opi = 0; opi < 2; ++opi) {
                #pragma unroll
                for (int nt = 0; nt < 2; ++nt) {
                    f32x4 t = __builtin_amdgcn_mfma_f32_16x16x32_bf16(al0, bl[opi][nt], z4, 0, 0, 0);
                    t = __builtin_amdgcn_mfma_f32_16x16x32_bf16(ah0, bl[opi][nt], t, 0, 0, 0);
                    t = __builtin_amdgcn_mfma_f32_16x16x32_bf16(al0, bh[opi][nt], t, 0, 0, 0);
                    acc[opi][0][nt] = __builtin_amdgcn_mfma_f32_16x16x32_bf16(ah0, bh[opi][nt], t, 0, 0, 0);
                    f32x4 u = __builtin_amdgcn_mfma_f32_16x16x32_bf16(al1, bl[opi][nt], z4, 0, 0, 0);
                    u = __builtin_amdgcn_mfma_f32_16x16x32_bf16(ah1, bl[opi][nt], u, 0, 0, 0);
                    u = __builtin_amdgcn_mfma_f32_16x16x32_bf16(al1, bh[opi][nt], u, 0, 0, 0);
                    acc[opi][1][nt] = __builtin_amdgcn_mfma_f32_16x16x32_bf16(ah1, bh[opi][nt], u, 0, 0, 0);
                }
            }

            // ---- stage 5: sign-fma + XOR-fold (values bit-identical to R15) ----
            float Y[2][2][4];
            #pragma unroll
            for (int opi = 0; opi < 2; ++opi)
                #pragma unroll
                for (int nt = 0; nt < 2; ++nt)
                    #pragma unroll
                    for (int r = 0; r < 4; ++r)
                        Y[opi][nt][r] = fmaf(sgn[nt * 4 + r],
                                             acc[opi][0][nt][r],
                                             sgn[8 + (nt ^ 1) * 4 + r] * acc[opi][1][nt ^ 1][r]);
            float Z[2][2];
            #pragma unroll
            for (int opi = 0; opi < 2; ++opi) {
                #pragma unroll
                for (int kt = 0; kt < 2; ++kt) {
                    float ya0 = Y[opi][kt][0] + dpp_xor1(Y[opi][kt][1]);
                    float ya2 = Y[opi][kt][2] + dpp_xor1(Y[opi][kt][3]);
                    float z = ya0 + dpp_xor2(ya2);
                    z += __shfl_xor(z, 20, 64);
                    z += __shfl_xor(z, 40, 64);
                    Z[opi][kt] = z;
                }
            }
            // select-by-own-g first (3 cndmask), then ONE bpermute from l_src
            float za  = (g & 2) ? Z[1][0] : Z[0][0];
            float zb  = (g & 2) ? Z[1][1] : Z[0][1];
            float sel = (g & 1) ? zb : za;
            const float delta = __shfl(sel, l_src, 64);

            // ---- stage 6: residual + L2 norm (R15-exact verified tail) ----
            float hc = h_reg + delta;
            float ss = hc * hc;
            ss += dpp_xor1(ss);
            ss += dpp_xor2(ss);
            ss += __shfl_xor(ss, 4, 32);
            ss += __shfl_xor(ss, 8, 32);
            ss += __shfl_xor(ss, 16, 32);
            h_reg = hc / (sqrtf(ss) + EPS_);

            // ---- stage 7: h_{s+1} -> parity p^1 ----
            ushort hh, hl; split2(h_reg, hh, hl);
            ghi[p ^ 1][eh] = hh; glo[p ^ 1][eh] = hl;
            hf[p ^ 1][oo * 32 + kk] = f2h(h_reg);    // slot == tid
        }

        xv_prev = xv_cur;
    }
}

extern "C" void kernel_launch(void* const* d_in, const int* in_sizes, int n_in,
                              void* d_out, int out_size, void* d_ws, size_t ws_size,
                              hipStream_t stream) {
    const float* x     = (const float*)d_in[0];
    const float* W_in  = (const float*)d_in[1];
    const float* b_in  = (const float*)d_in[2];
    const float* w_h   = (const float*)d_in[3];
    const float* w_x   = (const float*)d_in[4];
    const float* W_out = (const float*)d_in[5];
    const float* b_out = (const float*)d_in[6];
    float* outp = (float*)d_out;

    versor_kernel<<<256, 512, 0, stream>>>(x, W_in, b_in, w_h, w_x, W_out, b_out, outp);
}